// Round 6
// baseline (900.221 us; speedup 1.0000x reference)
//
#include <hip/hip_runtime.h>

#define NN 150000
#define EE 600000
#define HH 4
#define CC 64
#define GG 4096
#define INF 9

__device__ __forceinline__ float lrelu(float a){ return a > 0.f ? a : 0.2f*a; }

// ---------------- CSR build ----------------
__global__ __launch_bounds__(256) void k_count(const int* __restrict__ dst, int* __restrict__ deg){
  int e = blockIdx.x*256 + threadIdx.x;
  if (e < EE) atomicAdd(&deg[dst[e]], 1);
}

__global__ __launch_bounds__(256) void k_scan1(const int* __restrict__ deg, int* __restrict__ excl, int* __restrict__ bsum){
  __shared__ int s[256];
  int tid = threadIdx.x, gid = blockIdx.x*256 + tid;
  int v = (gid < NN) ? deg[gid] : 0;
  s[tid] = v; __syncthreads();
  for (int off = 1; off < 256; off <<= 1){
    int t = (tid >= off) ? s[tid-off] : 0; __syncthreads();
    s[tid] += t; __syncthreads();
  }
  if (gid < NN) excl[gid] = s[tid] - v;
  if (tid == 255) bsum[blockIdx.x] = s[255];
}

__global__ __launch_bounds__(1024) void k_scan2(int* __restrict__ bsum, int nb){
  __shared__ int s[1024];
  int tid = threadIdx.x;
  int v = (tid < nb) ? bsum[tid] : 0;
  s[tid] = v; __syncthreads();
  for (int off = 1; off < 1024; off <<= 1){
    int t = (tid >= off) ? s[tid-off] : 0; __syncthreads();
    s[tid] += t; __syncthreads();
  }
  if (tid < nb) bsum[tid] = s[tid] - v;
}

__global__ __launch_bounds__(256) void k_scan3(int* __restrict__ rp, const int* __restrict__ bsum){
  int gid = blockIdx.x*256 + threadIdx.x;
  if (gid < NN) rp[gid] += bsum[blockIdx.x];
  if (gid == 0) rp[NN] = EE;
}

__global__ __launch_bounds__(256) void k_fill(const int* __restrict__ src, const int* __restrict__ dst,
                                              const int* __restrict__ rp, int* __restrict__ fill,
                                              int* __restrict__ col){
  int e = blockIdx.x*256 + threadIdx.x;
  if (e < EE){
    int d = dst[e];
    int pos = rp[d] + atomicAdd(&fill[d], 1);
    col[pos] = src[e];
  }
}

__global__ __launch_bounds__(256) void k_gstart(const int* __restrict__ batch, int* __restrict__ gstart){
  int g = blockIdx.x*256 + threadIdx.x;
  if (g > GG) return;
  int lo = 0, hi = NN;
  while (lo < hi){ int mid = (lo+hi) >> 1; if (batch[mid] < g) lo = mid+1; else hi = mid; }
  gstart[g] = lo;
}

// ---------------- fold weights ----------------
__global__ __launch_bounds__(256) void k_fold(const float* __restrict__ g0W, const float* __restrict__ g0as,
    const float* __restrict__ g0ad, const float* __restrict__ gW, const float* __restrict__ gas,
    const float* __restrict__ gad, float* __restrict__ Wa0, float* __restrict__ Wa,
    float* __restrict__ Wstk0, float* __restrict__ Wstk){
  const int OFF1 = 72, OFF2 = OFF1 + 1536, OFF3 = OFF2 + 2304, OFF4 = OFF3 + 49152;
  int t = blockIdx.x*256 + threadIdx.x;
  if (t < OFF1){
    int k = t >> 3, j = t & 7, h = j & 3;
    const float* a = (j < 4) ? g0as : g0ad;
    float s = 0.f;
    for (int c = 0; c < 64; c++) s += g0W[k*256 + h*64 + c] * a[h*64 + c];
    Wa0[t] = s;
  } else if (t < OFF2){
    int u = t - OFF1;
    int i = u / 512, r = u % 512, k = r >> 3, j = r & 7, h = j & 3;
    const float* a = ((j < 4) ? gas : gad) + (size_t)i*256;
    float s = 0.f;
    for (int c = 0; c < 64; c++) s += gW[(size_t)i*16384 + k*256 + h*64 + c] * a[h*64 + c];
    Wa[u] = s;
  } else if (t < OFF3){
    int u = t - OFF2;           // u = k*64 + j, k = h*9+c
    int k = u >> 6, j = u & 63;
    int h = k / 9, c = k - h*9;
    Wstk0[u] = 0.25f * g0W[c*256 + h*64 + j];
  } else if (t < OFF4){
    int u = t - OFF3;           // u = i*16384 + k*64 + j, k = h*64+c
    int i = u >> 14, r = u & 16383;
    int k = r >> 6, j = r & 63;
    int h = k >> 6, c = k & 63;
    Wstk[u] = 0.25f * gW[(size_t)i*16384 + c*256 + h*64 + j];
  }
}

// ---------------- logits (layer 0 only): lg[n*8+j] = x[n,:9] @ Wa0[:,j] ----------------
__global__ __launch_bounds__(256) void k_logits9(const float* __restrict__ hin, const float* __restrict__ Wa,
                                                 float* __restrict__ lg){
  int idx = blockIdx.x*256 + threadIdx.x;
  int node = idx >> 3, j = idx & 7;
  if (node >= NN) return;
  const float* r = hin + (size_t)node*INF;
  float s = 0.f;
  #pragma unroll
  for (int k = 0; k < INF; k++) s += r[k] * Wa[k*8 + j];
  lg[(size_t)node*8 + j] = s;
}

// ---------------- aggregate RAW features per head (wave per node) ----------------
template<int KF>
__global__ __launch_bounds__(256) void k_aggA(const float* __restrict__ hin, const float* __restrict__ lg,
     const int* __restrict__ rp, const int* __restrict__ col, float* __restrict__ agg){
  int node = (blockIdx.x*256 + threadIdx.x) >> 6;
  int lane = threadIdx.x & 63;
  if (node >= NN) return;
  node = __builtin_amdgcn_readfirstlane(node);
  int rb = rp[node], re = rp[node+1];
  float4 esn = *(const float4*)(lg + (size_t)node*8);
  float4 edt = *(const float4*)(lg + (size_t)node*8 + 4);
  float edn[4] = {edt.x, edt.y, edt.z, edt.w};

  float den[4], acc[4];
  {
    float xv = (lane < KF) ? hin[(size_t)node*KF + lane] : 0.f;
    float a[4] = {esn.x, esn.y, esn.z, esn.w};
    #pragma unroll
    for (int h = 0; h < 4; h++){
      float ex = __expf(lrelu(a[h] + edn[h]));
      den[h] = ex; acc[h] = ex * xv;
    }
  }

  int e = rb;
  if (e < re){
    int sA = col[e];
    float4 tA = *(const float4*)(lg + (size_t)sA*8);
    float xA = (lane < KF) ? hin[(size_t)sA*KF + lane] : 0.f;
    for (; e < re; ){
      int en = e + 1;
      int sB = (en < re) ? col[en] : sA;
      float4 tB = *(const float4*)(lg + (size_t)sB*8);
      float xB = (lane < KF) ? hin[(size_t)sB*KF + lane] : 0.f;
      float ex0 = __expf(lrelu(tA.x + edn[0])); den[0] += ex0; acc[0] += ex0 * xA;
      float ex1 = __expf(lrelu(tA.y + edn[1])); den[1] += ex1; acc[1] += ex1 * xA;
      float ex2 = __expf(lrelu(tA.z + edn[2])); den[2] += ex2; acc[2] += ex2 * xA;
      float ex3 = __expf(lrelu(tA.w + edn[3])); den[3] += ex3; acc[3] += ex3 * xA;
      tA = tB; xA = xB;
      e = en;
    }
  }

  if (lane < KF){
    float* ap = agg + (size_t)node*(4*KF) + lane;
    #pragma unroll
    for (int h = 0; h < 4; h++) ap[h*KF] = acc[h] / den[h];
  }
}

// ---------------- transform + epilogue + next-layer logits ----------------
// 128 nodes x 64 cols per block, 256 threads = 4 waves.
// Thread (r=t>>4, c2=t&15) owns nodes 8r..8r+7 x cols 4c2..4c2+3 (8x4 register tile).
// Per k4 per wave: 12 ds_read_b128 (96 LDS cyc) vs 128 FMA instr (256 VALU cyc) -> VALU-bound.
// Both x-chunk and W-chunk in LDS (54.3 KB total incl Wa -> 3 blocks/CU).
// Epilogue: transpose via LDS, fused bias/BN/ELU/residual, and (if WaN) the NEXT layer's
// attention logits computed from the final h row sitting in LDS (saves a 38MB re-read).
template<int KK>
__global__ __launch_bounds__(256) void k_gemmB(const float* __restrict__ agg, const float* __restrict__ Ws,
    const float* __restrict__ bias, const float* __restrict__ gma, const float* __restrict__ bta,
    const float* __restrict__ mea, const float* __restrict__ var,
    const float* __restrict__ hres, float* __restrict__ hout,
    const float* __restrict__ WaN, float* __restrict__ lg){
  constexpr int CH   = (KK == 256) ? 64 : 36;   // K chunk
  constexpr int NCH  = KK / CH;
  constexpr int XSTR = (KK == 256) ? 68 : 44;   // x LDS stride (16B-aligned)
  constexpr int RF4  = CH / 4;
  __shared__ float xs[128*68];
  __shared__ float ws[64*68];
  __shared__ float wal[512];
  int t = threadIdx.x;
  int base = blockIdx.x * 128;
  int r = t >> 4, c2 = t & 15;

  if (WaN){ for (int i = t; i < 512; i += 256) wal[i] = WaN[i]; }

  float acc[8][4];
  #pragma unroll
  for (int i = 0; i < 8; i++)
    #pragma unroll
    for (int u = 0; u < 4; u++) acc[i][u] = 0.f;

  for (int ch = 0; ch < NCH; ch++){
    if (ch) __syncthreads();
    // stage x chunk: 128 nodes x CH k (coalesced float4)
    for (int i = t; i < 128*RF4; i += 256){
      int nd = i / RF4, kk = i - nd*RF4;
      float4 v = {0.f, 0.f, 0.f, 0.f};
      if (base + nd < NN) v = *(const float4*)(agg + (size_t)(base+nd)*KK + ch*CH + kk*4);
      *(float4*)(xs + nd*XSTR + kk*4) = v;
    }
    // stage W chunk: CH k x 64 cols
    for (int i = t; i < CH*16; i += 256){
      int k = i >> 4, c4 = i & 15;
      *(float4*)(ws + k*68 + c4*4) = *(const float4*)(Ws + (size_t)(ch*CH + k)*64 + c4*4);
    }
    __syncthreads();
    #pragma unroll 2
    for (int k4 = 0; k4 < CH; k4 += 4){
      float4 wv[4];
      #pragma unroll
      for (int u = 0; u < 4; u++) wv[u] = *(const float4*)(ws + (k4+u)*68 + 4*c2);
      #pragma unroll
      for (int i = 0; i < 8; i++){
        float4 xv = *(const float4*)(xs + (8*r+i)*XSTR + k4);
        acc[i][0] += xv.x*wv[0].x + xv.y*wv[1].x + xv.z*wv[2].x + xv.w*wv[3].x;
        acc[i][1] += xv.x*wv[0].y + xv.y*wv[1].y + xv.z*wv[2].y + xv.w*wv[3].y;
        acc[i][2] += xv.x*wv[0].z + xv.y*wv[1].z + xv.z*wv[2].z + xv.w*wv[3].z;
        acc[i][3] += xv.x*wv[0].w + xv.y*wv[1].w + xv.z*wv[2].w + xv.w*wv[3].w;
      }
    }
  }

  // transpose into xs as [node][col] (stride 68)
  __syncthreads();
  #pragma unroll
  for (int i = 0; i < 8; i++){
    float4 v = {acc[i][0], acc[i][1], acc[i][2], acc[i][3]};
    *(float4*)(xs + (8*r+i)*68 + 4*c2) = v;
  }
  __syncthreads();

  // fused epilogue; write final value back into xs for the logits pass
  int colj = t & 63, w = t >> 6;
  float bi = bias[colj], bt = bta[colj], me = mea[colj];
  float sc = rsqrtf(var[colj] + 1e-5f) * gma[colj];
  #pragma unroll 4
  for (int i = 0; i < 32; i++){
    int nd = 4*i + w;
    int node = base + nd;
    if (node < NN){
      float o = xs[nd*68 + colj] + bi;
      o = (o - me)*sc + bt;
      o = o > 0.f ? o : (__expf(o) - 1.f);
      if (hres) o += hres[(size_t)node*64 + colj];
      hout[(size_t)node*64 + colj] = o;
      xs[nd*68 + colj] = o;
    }
  }

  // next-layer logits: lg[node][j] = h[node,:] @ WaN[:,j]
  if (WaN){
    __syncthreads();
    int nd = t >> 1, jb = (t & 1) * 4;
    int node = base + nd;
    if (node < NN){
      float s0 = 0.f, s1 = 0.f, s2 = 0.f, s3 = 0.f;
      #pragma unroll 4
      for (int k = 0; k < 64; k += 4){
        float4 xv = *(const float4*)(xs + nd*68 + k);
        const float* wr = wal + k*8 + jb;
        s0 += xv.x*wr[0] + xv.y*wr[8]  + xv.z*wr[16] + xv.w*wr[24];
        s1 += xv.x*wr[1] + xv.y*wr[9]  + xv.z*wr[17] + xv.w*wr[25];
        s2 += xv.x*wr[2] + xv.y*wr[10] + xv.z*wr[18] + xv.w*wr[26];
        s3 += xv.x*wr[3] + xv.y*wr[11] + xv.z*wr[19] + xv.w*wr[27];
      }
      float4 sv = {s0, s1, s2, s3};
      *(float4*)(lg + (size_t)node*8 + jb) = sv;
    }
  }
}

// ---------------- pooling ----------------
__global__ __launch_bounds__(64) void k_pool(const float* __restrict__ h, const int* __restrict__ gstart,
                                             float* __restrict__ pooled){
  int g = blockIdx.x; int lane = threadIdx.x;
  int beg = gstart[g], end = gstart[g+1];
  float acc = 0.f;
  for (int n = beg; n < end; n++) acc += h[(size_t)n*64 + lane];
  float cnt = (float)(end - beg);
  pooled[(size_t)g*64 + lane] = acc / fmaxf(cnt, 1.f);
}

// ---------------- output MLP ----------------
__global__ __launch_bounds__(256) void k_mlp(const float* __restrict__ pooled, const float* __restrict__ W1,
                                             const float* __restrict__ b1, const float* __restrict__ W2,
                                             const float* __restrict__ b2, float* __restrict__ out){
  int g = blockIdx.x*256 + threadIdx.x;
  if (g >= GG) return;
  const float* p = pooled + (size_t)g*64;
  float o = 0.f;
  for (int j = 0; j < 32; j++){
    float z = b1[j];
    for (int c = 0; c < 64; c++) z += p[c] * W1[c*32 + j];
    z = z > 0.f ? z : (__expf(z) - 1.f);
    o += z * W2[j];
  }
  out[g] = o + b2[0];
}

extern "C" void kernel_launch(void* const* d_in, const int* in_sizes, int n_in,
                              void* d_out, int out_size, void* d_ws, size_t ws_size,
                              hipStream_t stream) {
  const float* x    = (const float*)d_in[0];
  const int*   ei   = (const int*)d_in[1];
  const int*   batch= (const int*)d_in[2];
  const float* g0W  = (const float*)d_in[3];
  const float* g0as = (const float*)d_in[4];
  const float* g0ad = (const float*)d_in[5];
  const float* g0b  = (const float*)d_in[6];
  const float* bn0g = (const float*)d_in[7];
  const float* bn0b = (const float*)d_in[8];
  const float* bn0m = (const float*)d_in[9];
  const float* bn0v = (const float*)d_in[10];
  const float* gW   = (const float*)d_in[11];
  const float* gas  = (const float*)d_in[12];
  const float* gad  = (const float*)d_in[13];
  const float* gb   = (const float*)d_in[14];
  const float* bng  = (const float*)d_in[15];
  const float* bnb  = (const float*)d_in[16];
  const float* bnm  = (const float*)d_in[17];
  const float* bnv  = (const float*)d_in[18];
  const float* W1   = (const float*)d_in[19];
  const float* b1   = (const float*)d_in[20];
  const float* W2   = (const float*)d_in[21];
  const float* b2   = (const float*)d_in[22];
  float* out = (float*)d_out;
  (void)in_sizes; (void)n_in; (void)out_size; (void)ws_size;

  char* base = (char*)d_ws; size_t off = 0;
  auto alloc = [&](size_t b)->void*{ void* p = base + off; off = (off + b + 255) & ~(size_t)255; return p; };
  float* agg    = (float*)alloc((size_t)NN*256*4);   // 153.6 MB ([N,36] for layer 0)
  float* h_cur  = (float*)alloc((size_t)NN*64*4);    // 38.4 MB
  float* lg     = (float*)alloc((size_t)NN*8*4);     // 4.8 MB
  int*   deg    = (int*)alloc((size_t)NN*4);
  int*   fill   = (int*)alloc((size_t)NN*4);
  int*   rp     = (int*)alloc((size_t)(NN+1)*4);
  int*   col    = (int*)alloc((size_t)EE*4);
  int*   bsum   = (int*)alloc(1024*4);
  int*   gstart = (int*)alloc((size_t)(GG+1)*4);
  float* pooled = (float*)alloc((size_t)GG*64*4);
  float* Wa0    = (float*)alloc((size_t)72*4);
  float* Wa     = (float*)alloc((size_t)1536*4);
  float* Wstk0  = (float*)alloc((size_t)2304*4);
  float* Wstk   = (float*)alloc((size_t)49152*4);

  const int* esrc = ei;
  const int* edst = ei + EE;

  hipMemsetAsync(deg, 0, (size_t)NN*4, stream);
  hipMemsetAsync(fill, 0, (size_t)NN*4, stream);

  int nb1 = (NN + 255)/256;
  k_count<<<(EE+255)/256, 256, 0, stream>>>(edst, deg);
  k_scan1<<<nb1, 256, 0, stream>>>(deg, rp, bsum);
  k_scan2<<<1, 1024, 0, stream>>>(bsum, nb1);
  k_scan3<<<nb1, 256, 0, stream>>>(rp, bsum);
  k_fill<<<(EE+255)/256, 256, 0, stream>>>(esrc, edst, rp, fill, col);
  k_gstart<<<(GG+256)/256, 256, 0, stream>>>(batch, gstart);
  k_fold<<<208, 256, 0, stream>>>(g0W, g0as, g0ad, gW, gas, gad, Wa0, Wa, Wstk0, Wstk);

  int nlog  = (NN*8 + 255)/256;   // 4688
  int nwave = NN/4;               // 37500
  int ngB   = (NN + 127)/128;     // 1172

  // layer 0 (logits for layer 1 fused into gemmB via WaN = Wa[0])
  k_logits9<<<nlog, 256, 0, stream>>>(x, Wa0, lg);
  k_aggA<INF><<<nwave, 256, 0, stream>>>(x, lg, rp, col, agg);
  k_gemmB<36><<<ngB, 256, 0, stream>>>(agg, Wstk0, g0b, bn0g, bn0b, bn0m, bn0v,
                                       nullptr, h_cur, Wa, lg);
  // layers 1..3
  for (int i = 0; i < 3; i++){
    k_aggA<CC><<<nwave, 256, 0, stream>>>(h_cur, lg, rp, col, agg);
    k_gemmB<256><<<ngB, 256, 0, stream>>>(agg, Wstk + (size_t)i*16384, gb + (size_t)i*64,
                                          bng + (size_t)i*64, bnb + (size_t)i*64,
                                          bnm + (size_t)i*64, bnv + (size_t)i*64,
                                          h_cur, h_cur,
                                          (i < 2) ? (Wa + (size_t)(i+1)*512) : nullptr, lg);
  }

  k_pool<<<GG, 64, 0, stream>>>(h_cur, gstart, pooled);
  k_mlp<<<(GG+255)/256, 256, 0, stream>>>(pooled, W1, b1, W2, b2, out);
}

// Round 7
// 721.066 us; speedup vs baseline: 1.2485x; 1.2485x over previous
//
#include <hip/hip_runtime.h>

#define NN 150000
#define EE 600000
#define HH 4
#define CC 64
#define GG 4096
#define INF 9

__device__ __forceinline__ float lrelu(float a){ return a > 0.f ? a : 0.2f*a; }
__device__ __forceinline__ float b2f(unsigned short u){ return __uint_as_float((unsigned)u << 16); }
__device__ __forceinline__ unsigned short f2b(float f){
  unsigned u = __float_as_uint(f);
  return (unsigned short)((u + 0x7fff + ((u >> 16) & 1)) >> 16);   // RNE
}

// ---------------- CSR build ----------------
__global__ __launch_bounds__(256) void k_count(const int* __restrict__ dst, int* __restrict__ deg){
  int e = blockIdx.x*256 + threadIdx.x;
  if (e < EE) atomicAdd(&deg[dst[e]], 1);
}

__global__ __launch_bounds__(256) void k_scan1(const int* __restrict__ deg, int* __restrict__ excl, int* __restrict__ bsum){
  __shared__ int s[256];
  int tid = threadIdx.x, gid = blockIdx.x*256 + tid;
  int v = (gid < NN) ? deg[gid] : 0;
  s[tid] = v; __syncthreads();
  for (int off = 1; off < 256; off <<= 1){
    int t = (tid >= off) ? s[tid-off] : 0; __syncthreads();
    s[tid] += t; __syncthreads();
  }
  if (gid < NN) excl[gid] = s[tid] - v;
  if (tid == 255) bsum[blockIdx.x] = s[255];
}

__global__ __launch_bounds__(1024) void k_scan2(int* __restrict__ bsum, int nb){
  __shared__ int s[1024];
  int tid = threadIdx.x;
  int v = (tid < nb) ? bsum[tid] : 0;
  s[tid] = v; __syncthreads();
  for (int off = 1; off < 1024; off <<= 1){
    int t = (tid >= off) ? s[tid-off] : 0; __syncthreads();
    s[tid] += t; __syncthreads();
  }
  if (tid < nb) bsum[tid] = s[tid] - v;
}

__global__ __launch_bounds__(256) void k_scan3(int* __restrict__ rp, const int* __restrict__ bsum){
  int gid = blockIdx.x*256 + threadIdx.x;
  if (gid < NN) rp[gid] += bsum[blockIdx.x];
  if (gid == 0) rp[NN] = EE;
}

__global__ __launch_bounds__(256) void k_fill(const int* __restrict__ src, const int* __restrict__ dst,
                                              const int* __restrict__ rp, int* __restrict__ fill,
                                              int* __restrict__ col){
  int e = blockIdx.x*256 + threadIdx.x;
  if (e < EE){
    int d = dst[e];
    int pos = rp[d] + atomicAdd(&fill[d], 1);
    col[pos] = src[e];
  }
}

__global__ __launch_bounds__(256) void k_gstart(const int* __restrict__ batch, int* __restrict__ gstart){
  int g = blockIdx.x*256 + threadIdx.x;
  if (g > GG) return;
  int lo = 0, hi = NN;
  while (lo < hi){ int mid = (lo+hi) >> 1; if (batch[mid] < g) lo = mid+1; else hi = mid; }
  gstart[g] = lo;
}

// ---------------- fold weights ----------------
__global__ __launch_bounds__(256) void k_fold(const float* __restrict__ g0W, const float* __restrict__ g0as,
    const float* __restrict__ g0ad, const float* __restrict__ gW, const float* __restrict__ gas,
    const float* __restrict__ gad, float* __restrict__ Wa0, float* __restrict__ Wa,
    float* __restrict__ Wstk0, float* __restrict__ Wstk){
  const int OFF1 = 72, OFF2 = OFF1 + 1536, OFF3 = OFF2 + 2304, OFF4 = OFF3 + 49152;
  int t = blockIdx.x*256 + threadIdx.x;
  if (t < OFF1){
    int k = t >> 3, j = t & 7, h = j & 3;
    const float* a = (j < 4) ? g0as : g0ad;
    float s = 0.f;
    for (int c = 0; c < 64; c++) s += g0W[k*256 + h*64 + c] * a[h*64 + c];
    Wa0[t] = s;
  } else if (t < OFF2){
    int u = t - OFF1;
    int i = u / 512, r = u % 512, k = r >> 3, j = r & 7, h = j & 3;
    const float* a = ((j < 4) ? gas : gad) + (size_t)i*256;
    float s = 0.f;
    for (int c = 0; c < 64; c++) s += gW[(size_t)i*16384 + k*256 + h*64 + c] * a[h*64 + c];
    Wa[u] = s;
  } else if (t < OFF3){
    int u = t - OFF2;           // u = k*64 + j, k = h*9+c
    int k = u >> 6, j = u & 63;
    int h = k / 9, c = k - h*9;
    Wstk0[u] = 0.25f * g0W[c*256 + h*64 + j];
  } else if (t < OFF4){
    int u = t - OFF3;           // u = i*16384 + k*64 + j, k = h*64+c
    int i = u >> 14, r = u & 16383;
    int k = r >> 6, j = r & 63;
    int h = k >> 6, c = k & 63;
    Wstk[u] = 0.25f * gW[(size_t)i*16384 + c*256 + h*64 + j];
  }
}

// ---------------- logits (layer 0 only): lg[n*8+j] = x[n,:9] @ Wa0[:,j] ----------------
__global__ __launch_bounds__(256) void k_logits9(const float* __restrict__ hin, const float* __restrict__ Wa,
                                                 float* __restrict__ lg){
  int idx = blockIdx.x*256 + threadIdx.x;
  int node = idx >> 3, j = idx & 7;
  if (node >= NN) return;
  const float* r = hin + (size_t)node*INF;
  float s = 0.f;
  #pragma unroll
  for (int k = 0; k < INF; k++) s += r[k] * Wa[k*8 + j];
  lg[(size_t)node*8 + j] = s;
}

// ---------------- layer-0 aggregation (f32 x, f32 agg32[N,36]) ----------------
__global__ __launch_bounds__(256) void k_aggA9(const float* __restrict__ hin, const float* __restrict__ lg,
     const int* __restrict__ rp, const int* __restrict__ col, float* __restrict__ agg){
  int node = (blockIdx.x*256 + threadIdx.x) >> 6;
  int lane = threadIdx.x & 63;
  if (node >= NN) return;
  node = __builtin_amdgcn_readfirstlane(node);
  int rb = rp[node], re = rp[node+1];
  float4 esn = *(const float4*)(lg + (size_t)node*8);
  float4 edt = *(const float4*)(lg + (size_t)node*8 + 4);
  float edn[4] = {edt.x, edt.y, edt.z, edt.w};

  float den[4], acc[4];
  {
    float xv = (lane < INF) ? hin[(size_t)node*INF + lane] : 0.f;
    float a[4] = {esn.x, esn.y, esn.z, esn.w};
    #pragma unroll
    for (int h = 0; h < 4; h++){
      float ex = __expf(lrelu(a[h] + edn[h]));
      den[h] = ex; acc[h] = ex * xv;
    }
  }
  int e = rb;
  if (e < re){
    int sA = col[e];
    float4 tA = *(const float4*)(lg + (size_t)sA*8);
    float xA = (lane < INF) ? hin[(size_t)sA*INF + lane] : 0.f;
    for (; e < re; ){
      int en = e + 1;
      int sB = (en < re) ? col[en] : sA;
      float4 tB = *(const float4*)(lg + (size_t)sB*8);
      float xB = (lane < INF) ? hin[(size_t)sB*INF + lane] : 0.f;
      float ex0 = __expf(lrelu(tA.x + edn[0])); den[0] += ex0; acc[0] += ex0 * xA;
      float ex1 = __expf(lrelu(tA.y + edn[1])); den[1] += ex1; acc[1] += ex1 * xA;
      float ex2 = __expf(lrelu(tA.z + edn[2])); den[2] += ex2; acc[2] += ex2 * xA;
      float ex3 = __expf(lrelu(tA.w + edn[3])); den[3] += ex3; acc[3] += ex3 * xA;
      tA = tB; xA = xB;
      e = en;
    }
  }
  if (lane < INF){
    float* ap = agg + (size_t)node*36 + lane;
    #pragma unroll
    for (int h = 0; h < 4; h++) ap[h*INF] = acc[h] / den[h];
  }
}

// ---------------- layers 1-3 aggregation (bf16 gather, bf16 agg[N,256]) ----------------
__global__ __launch_bounds__(256) void k_aggAb(const unsigned short* __restrict__ hb, const float* __restrict__ lg,
     const int* __restrict__ rp, const int* __restrict__ col, unsigned short* __restrict__ aggb){
  int node = (blockIdx.x*256 + threadIdx.x) >> 6;
  int lane = threadIdx.x & 63;
  if (node >= NN) return;
  node = __builtin_amdgcn_readfirstlane(node);
  int rb = rp[node], re = rp[node+1];
  float4 esn = *(const float4*)(lg + (size_t)node*8);
  float4 edt = *(const float4*)(lg + (size_t)node*8 + 4);
  float edn[4] = {edt.x, edt.y, edt.z, edt.w};

  float den[4], acc[4];
  {
    float xv = b2f(hb[(size_t)node*64 + lane]);
    float a[4] = {esn.x, esn.y, esn.z, esn.w};
    #pragma unroll
    for (int h = 0; h < 4; h++){
      float ex = __expf(lrelu(a[h] + edn[h]));
      den[h] = ex; acc[h] = ex * xv;
    }
  }
  int e = rb;
  if (e < re){
    int sA = col[e];
    float4 tA = *(const float4*)(lg + (size_t)sA*8);
    float xA = b2f(hb[(size_t)sA*64 + lane]);
    for (; e < re; ){
      int en = e + 1;
      int sB = (en < re) ? col[en] : sA;
      float4 tB = *(const float4*)(lg + (size_t)sB*8);
      float xB = b2f(hb[(size_t)sB*64 + lane]);
      float ex0 = __expf(lrelu(tA.x + edn[0])); den[0] += ex0; acc[0] += ex0 * xA;
      float ex1 = __expf(lrelu(tA.y + edn[1])); den[1] += ex1; acc[1] += ex1 * xA;
      float ex2 = __expf(lrelu(tA.z + edn[2])); den[2] += ex2; acc[2] += ex2 * xA;
      float ex3 = __expf(lrelu(tA.w + edn[3])); den[3] += ex3; acc[3] += ex3 * xA;
      tA = tB; xA = xB;
      e = en;
    }
  }
  #pragma unroll
  for (int h = 0; h < 4; h++)
    aggb[(size_t)node*256 + h*64 + lane] = f2b(acc[h] / den[h]);
}

// ---------------- layer-0 transform (f32 agg32[N,36]) + epilogue + layer-1 logits ----------------
// Round-4 structure: 64 nodes x 64 cols, 4x4 thread tile, x+W in LDS, 4 blocks/CU.
__global__ __launch_bounds__(256) void k_gemmB36(const float* __restrict__ agg, const float* __restrict__ Ws,
    const float* __restrict__ bias, const float* __restrict__ gma, const float* __restrict__ bta,
    const float* __restrict__ mea, const float* __restrict__ var,
    float* __restrict__ hout, unsigned short* __restrict__ hbf,
    const float* __restrict__ WaN, float* __restrict__ lg){
  __shared__ float xs[64*68];
  __shared__ float ws[64*68];
  __shared__ float wal[512];
  int t = threadIdx.x;
  int base = blockIdx.x * 64;
  int r = t >> 4, c2 = t & 15;
  for (int i = t; i < 512; i += 256) wal[i] = WaN[i];

  // stage x: 64 nodes x 36 k (stride 44)
  for (int i = t; i < 64*9; i += 256){
    int nd = i / 9, kk = i - nd*9;
    float4 v = {0.f,0.f,0.f,0.f};
    if (base + nd < NN) v = *(const float4*)(agg + (size_t)(base+nd)*36 + kk*4);
    *(float4*)(xs + nd*44 + kk*4) = v;
  }
  // stage W: 36 k x 64 c (stride 68)
  for (int i = t; i < 36*16; i += 256){
    int k = i >> 4, c4 = i & 15;
    *(float4*)(ws + k*68 + c4*4) = *(const float4*)(Ws + (size_t)k*64 + c4*4);
  }
  __syncthreads();

  float acc[4][4];
  #pragma unroll
  for (int i = 0; i < 4; i++)
    #pragma unroll
    for (int u = 0; u < 4; u++) acc[i][u] = 0.f;

  for (int k4 = 0; k4 < 36; k4 += 4){
    float4 xv[4], wv[4];
    #pragma unroll
    for (int i = 0; i < 4; i++) xv[i] = *(const float4*)(xs + (4*r+i)*44 + k4);
    #pragma unroll
    for (int u = 0; u < 4; u++) wv[u] = *(const float4*)(ws + (k4+u)*68 + 4*c2);
    #pragma unroll
    for (int i = 0; i < 4; i++){
      float xr[4] = {xv[i].x, xv[i].y, xv[i].z, xv[i].w};
      #pragma unroll
      for (int u = 0; u < 4; u++){
        acc[i][0] += xr[u]*wv[u].x; acc[i][1] += xr[u]*wv[u].y;
        acc[i][2] += xr[u]*wv[u].z; acc[i][3] += xr[u]*wv[u].w;
      }
    }
  }

  // epilogue (no residual for layer 0)
  int cb = 4*c2;
  float4 bi = *(const float4*)(bias + cb);
  float4 gm = *(const float4*)(gma + cb);
  float4 bt = *(const float4*)(bta + cb);
  float4 me = *(const float4*)(mea + cb);
  float4 va = *(const float4*)(var + cb);
  float sc0 = rsqrtf(va.x + 1e-5f)*gm.x, sc1 = rsqrtf(va.y + 1e-5f)*gm.y;
  float sc2 = rsqrtf(va.z + 1e-5f)*gm.z, sc3 = rsqrtf(va.w + 1e-5f)*gm.w;
  __syncthreads();
  #pragma unroll
  for (int i = 0; i < 4; i++){
    int node = base + 4*r + i;
    if (node < NN){
      float o0 = (acc[i][0] + bi.x - me.x)*sc0 + bt.x;
      float o1 = (acc[i][1] + bi.y - me.y)*sc1 + bt.y;
      float o2 = (acc[i][2] + bi.z - me.z)*sc2 + bt.z;
      float o3 = (acc[i][3] + bi.w - me.w)*sc3 + bt.w;
      o0 = o0 > 0.f ? o0 : (__expf(o0) - 1.f);
      o1 = o1 > 0.f ? o1 : (__expf(o1) - 1.f);
      o2 = o2 > 0.f ? o2 : (__expf(o2) - 1.f);
      o3 = o3 > 0.f ? o3 : (__expf(o3) - 1.f);
      float4 st = {o0, o1, o2, o3};
      *(float4*)(hout + (size_t)node*64 + cb) = st;
      uint2 pb = { (unsigned)f2b(o0) | ((unsigned)f2b(o1) << 16),
                   (unsigned)f2b(o2) | ((unsigned)f2b(o3) << 16) };
      *(uint2*)(hbf + (size_t)node*64 + cb) = pb;
      *(float4*)(xs + (4*r+i)*68 + cb) = st;
    }
  }
  // next-layer logits from the h row in LDS
  __syncthreads();
  int nd = t >> 2, jq = (t & 3) * 2;
  int node = base + nd;
  if (node < NN){
    float s0 = 0.f, s1 = 0.f;
    #pragma unroll 4
    for (int k = 0; k < 64; k += 4){
      float4 xv = *(const float4*)(xs + nd*68 + k);
      const float* w0 = wal + k*8 + jq;
      s0 += xv.x*w0[0] + xv.y*w0[8] + xv.z*w0[16] + xv.w*w0[24];
      s1 += xv.x*w0[1] + xv.y*w0[9] + xv.z*w0[17] + xv.w*w0[25];
    }
    float2 sv = {s0, s1};
    *(float2*)(lg + (size_t)node*8 + jq) = sv;
  }
}

// ---------------- layers 1-3 transform (bf16 agg[N,256]) + epilogue + next logits ----------------
template<bool LOGITS>
__global__ __launch_bounds__(256) void k_gemmB256(const unsigned short* __restrict__ aggb, const float* __restrict__ Ws,
    const float* __restrict__ bias, const float* __restrict__ gma, const float* __restrict__ bta,
    const float* __restrict__ mea, const float* __restrict__ var,
    const float* __restrict__ hres, float* __restrict__ hout, unsigned short* __restrict__ hbf,
    const float* __restrict__ WaN, float* __restrict__ lg){
  __shared__ float xs[64*68];
  __shared__ float ws[64*68];
  __shared__ float wal[512];
  int t = threadIdx.x;
  int base = blockIdx.x * 64;
  int r = t >> 4, c2 = t & 15;
  if (LOGITS){ for (int i = t; i < 512; i += 256) wal[i] = WaN[i]; }

  float acc[4][4];
  #pragma unroll
  for (int i = 0; i < 4; i++)
    #pragma unroll
    for (int u = 0; u < 4; u++) acc[i][u] = 0.f;

  for (int ch = 0; ch < 4; ch++){
    if (ch) __syncthreads();
    // stage x chunk: 64 nodes x 64 k, bf16 -> f32 LDS (stride 68)
    for (int i = t; i < 512; i += 256){
      int nd = i >> 3, g = i & 7;
      int node = base + nd;
      uint4 q = {0u,0u,0u,0u};
      if (node < NN) q = *(const uint4*)(aggb + (size_t)node*256 + ch*64 + g*8);
      float4 a, b;
      a.x = __uint_as_float(q.x << 16); a.y = __uint_as_float(q.x & 0xffff0000u);
      a.z = __uint_as_float(q.y << 16); a.w = __uint_as_float(q.y & 0xffff0000u);
      b.x = __uint_as_float(q.z << 16); b.y = __uint_as_float(q.z & 0xffff0000u);
      b.z = __uint_as_float(q.w << 16); b.w = __uint_as_float(q.w & 0xffff0000u);
      *(float4*)(xs + nd*68 + g*8)     = a;
      *(float4*)(xs + nd*68 + g*8 + 4) = b;
    }
    // stage W chunk: 64 k x 64 c (stride 68)
    for (int i = t; i < 64*16; i += 256){
      int k = i >> 4, c4 = i & 15;
      *(float4*)(ws + k*68 + c4*4) = *(const float4*)(Ws + (size_t)(ch*64 + k)*64 + c4*4);
    }
    __syncthreads();
    #pragma unroll 2
    for (int k4 = 0; k4 < 64; k4 += 4){
      float4 xv[4], wv[4];
      #pragma unroll
      for (int i = 0; i < 4; i++) xv[i] = *(const float4*)(xs + (4*r+i)*68 + k4);
      #pragma unroll
      for (int u = 0; u < 4; u++) wv[u] = *(const float4*)(ws + (k4+u)*68 + 4*c2);
      #pragma unroll
      for (int i = 0; i < 4; i++){
        float xr[4] = {xv[i].x, xv[i].y, xv[i].z, xv[i].w};
        #pragma unroll
        for (int u = 0; u < 4; u++){
          acc[i][0] += xr[u]*wv[u].x; acc[i][1] += xr[u]*wv[u].y;
          acc[i][2] += xr[u]*wv[u].z; acc[i][3] += xr[u]*wv[u].w;
        }
      }
    }
  }

  // epilogue with residual; write back into xs for the logits pass
  int cb = 4*c2;
  float4 bi = *(const float4*)(bias + cb);
  float4 gm = *(const float4*)(gma + cb);
  float4 bt = *(const float4*)(bta + cb);
  float4 me = *(const float4*)(mea + cb);
  float4 va = *(const float4*)(var + cb);
  float sc0 = rsqrtf(va.x + 1e-5f)*gm.x, sc1 = rsqrtf(va.y + 1e-5f)*gm.y;
  float sc2 = rsqrtf(va.z + 1e-5f)*gm.z, sc3 = rsqrtf(va.w + 1e-5f)*gm.w;
  __syncthreads();
  #pragma unroll
  for (int i = 0; i < 4; i++){
    int node = base + 4*r + i;
    if (node < NN){
      float o0 = (acc[i][0] + bi.x - me.x)*sc0 + bt.x;
      float o1 = (acc[i][1] + bi.y - me.y)*sc1 + bt.y;
      float o2 = (acc[i][2] + bi.z - me.z)*sc2 + bt.z;
      float o3 = (acc[i][3] + bi.w - me.w)*sc3 + bt.w;
      o0 = o0 > 0.f ? o0 : (__expf(o0) - 1.f);
      o1 = o1 > 0.f ? o1 : (__expf(o1) - 1.f);
      o2 = o2 > 0.f ? o2 : (__expf(o2) - 1.f);
      o3 = o3 > 0.f ? o3 : (__expf(o3) - 1.f);
      float4 rv = *(const float4*)(hres + (size_t)node*64 + cb);
      o0 += rv.x; o1 += rv.y; o2 += rv.z; o3 += rv.w;
      float4 st = {o0, o1, o2, o3};
      *(float4*)(hout + (size_t)node*64 + cb) = st;
      if (LOGITS){
        uint2 pb = { (unsigned)f2b(o0) | ((unsigned)f2b(o1) << 16),
                     (unsigned)f2b(o2) | ((unsigned)f2b(o3) << 16) };
        *(uint2*)(hbf + (size_t)node*64 + cb) = pb;
        *(float4*)(xs + (4*r+i)*68 + cb) = st;
      }
    }
  }
  if (LOGITS){
    __syncthreads();
    int nd = t >> 2, jq = (t & 3) * 2;
    int node = base + nd;
    if (node < NN){
      float s0 = 0.f, s1 = 0.f;
      #pragma unroll 4
      for (int k = 0; k < 64; k += 4){
        float4 xv = *(const float4*)(xs + nd*68 + k);
        const float* w0 = wal + k*8 + jq;
        s0 += xv.x*w0[0] + xv.y*w0[8] + xv.z*w0[16] + xv.w*w0[24];
        s1 += xv.x*w0[1] + xv.y*w0[9] + xv.z*w0[17] + xv.w*w0[25];
      }
      float2 sv = {s0, s1};
      *(float2*)(lg + (size_t)node*8 + jq) = sv;
    }
  }
}

// ---------------- pooling ----------------
__global__ __launch_bounds__(64) void k_pool(const float* __restrict__ h, const int* __restrict__ gstart,
                                             float* __restrict__ pooled){
  int g = blockIdx.x; int lane = threadIdx.x;
  int beg = gstart[g], end = gstart[g+1];
  float acc = 0.f;
  for (int n = beg; n < end; n++) acc += h[(size_t)n*64 + lane];
  float cnt = (float)(end - beg);
  pooled[(size_t)g*64 + lane] = acc / fmaxf(cnt, 1.f);
}

// ---------------- output MLP ----------------
__global__ __launch_bounds__(256) void k_mlp(const float* __restrict__ pooled, const float* __restrict__ W1,
                                             const float* __restrict__ b1, const float* __restrict__ W2,
                                             const float* __restrict__ b2, float* __restrict__ out){
  int g = blockIdx.x*256 + threadIdx.x;
  if (g >= GG) return;
  const float* p = pooled + (size_t)g*64;
  float o = 0.f;
  for (int j = 0; j < 32; j++){
    float z = b1[j];
    for (int c = 0; c < 64; c++) z += p[c] * W1[c*32 + j];
    z = z > 0.f ? z : (__expf(z) - 1.f);
    o += z * W2[j];
  }
  out[g] = o + b2[0];
}

extern "C" void kernel_launch(void* const* d_in, const int* in_sizes, int n_in,
                              void* d_out, int out_size, void* d_ws, size_t ws_size,
                              hipStream_t stream) {
  const float* x    = (const float*)d_in[0];
  const int*   ei   = (const int*)d_in[1];
  const int*   batch= (const int*)d_in[2];
  const float* g0W  = (const float*)d_in[3];
  const float* g0as = (const float*)d_in[4];
  const float* g0ad = (const float*)d_in[5];
  const float* g0b  = (const float*)d_in[6];
  const float* bn0g = (const float*)d_in[7];
  const float* bn0b = (const float*)d_in[8];
  const float* bn0m = (const float*)d_in[9];
  const float* bn0v = (const float*)d_in[10];
  const float* gW   = (const float*)d_in[11];
  const float* gas  = (const float*)d_in[12];
  const float* gad  = (const float*)d_in[13];
  const float* gb   = (const float*)d_in[14];
  const float* bng  = (const float*)d_in[15];
  const float* bnb  = (const float*)d_in[16];
  const float* bnm  = (const float*)d_in[17];
  const float* bnv  = (const float*)d_in[18];
  const float* W1   = (const float*)d_in[19];
  const float* b1   = (const float*)d_in[20];
  const float* W2   = (const float*)d_in[21];
  const float* b2   = (const float*)d_in[22];
  float* out = (float*)d_out;
  (void)in_sizes; (void)n_in; (void)out_size; (void)ws_size;

  char* base = (char*)d_ws; size_t off = 0;
  auto alloc = [&](size_t b)->void*{ void* p = base + off; off = (off + b + 255) & ~(size_t)255; return p; };
  unsigned short* aggb = (unsigned short*)alloc((size_t)NN*256*2);  // 76.8 MB (layers 1-3)
  float* agg32  = (float*)alloc((size_t)NN*36*4);                   // 21.6 MB (layer 0)
  float* h_cur  = (float*)alloc((size_t)NN*64*4);                   // 38.4 MB
  unsigned short* hbf = (unsigned short*)alloc((size_t)NN*64*2);    // 19.2 MB
  float* lg     = (float*)alloc((size_t)NN*8*4);                    // 4.8 MB
  int*   deg    = (int*)alloc((size_t)NN*4);
  int*   fill   = (int*)alloc((size_t)NN*4);
  int*   rp     = (int*)alloc((size_t)(NN+1)*4);
  int*   col    = (int*)alloc((size_t)EE*4);
  int*   bsum   = (int*)alloc(1024*4);
  int*   gstart = (int*)alloc((size_t)(GG+1)*4);
  float* pooled = (float*)alloc((size_t)GG*64*4);
  float* Wa0    = (float*)alloc((size_t)72*4);
  float* Wa     = (float*)alloc((size_t)1536*4);
  float* Wstk0  = (float*)alloc((size_t)2304*4);
  float* Wstk   = (float*)alloc((size_t)49152*4);

  const int* esrc = ei;
  const int* edst = ei + EE;

  hipMemsetAsync(deg, 0, (size_t)NN*4, stream);
  hipMemsetAsync(fill, 0, (size_t)NN*4, stream);

  int nb1 = (NN + 255)/256;
  k_count<<<(EE+255)/256, 256, 0, stream>>>(edst, deg);
  k_scan1<<<nb1, 256, 0, stream>>>(deg, rp, bsum);
  k_scan2<<<1, 1024, 0, stream>>>(bsum, nb1);
  k_scan3<<<nb1, 256, 0, stream>>>(rp, bsum);
  k_fill<<<(EE+255)/256, 256, 0, stream>>>(esrc, edst, rp, fill, col);
  k_gstart<<<(GG+256)/256, 256, 0, stream>>>(batch, gstart);
  k_fold<<<208, 256, 0, stream>>>(g0W, g0as, g0ad, gW, gas, gad, Wa0, Wa, Wstk0, Wstk);

  int nlog  = (NN*8 + 255)/256;   // 4688
  int nwave = NN/4;               // 37500
  int ngB   = (NN + 63)/64;       // 2344

  // layer 0 (layer-1 logits fused into gemmB via WaN = Wa[0])
  k_logits9<<<nlog, 256, 0, stream>>>(x, Wa0, lg);
  k_aggA9<<<nwave, 256, 0, stream>>>(x, lg, rp, col, agg32);
  k_gemmB36<<<ngB, 256, 0, stream>>>(agg32, Wstk0, g0b, bn0g, bn0b, bn0m, bn0v,
                                     h_cur, hbf, Wa, lg);
  // layers 1..3
  for (int i = 0; i < 3; i++){
    k_aggAb<<<nwave, 256, 0, stream>>>(hbf, lg, rp, col, aggb);
    if (i < 2)
      k_gemmB256<true><<<ngB, 256, 0, stream>>>(aggb, Wstk + (size_t)i*16384, gb + (size_t)i*64,
                                                bng + (size_t)i*64, bnb + (size_t)i*64,
                                                bnm + (size_t)i*64, bnv + (size_t)i*64,
                                                h_cur, h_cur, hbf, Wa + (size_t)(i+1)*512, lg);
    else
      k_gemmB256<false><<<ngB, 256, 0, stream>>>(aggb, Wstk + (size_t)i*16384, gb + (size_t)i*64,
                                                 bng + (size_t)i*64, bnb + (size_t)i*64,
                                                 bnm + (size_t)i*64, bnv + (size_t)i*64,
                                                 h_cur, h_cur, hbf, nullptr, nullptr);
  }

  k_pool<<<GG, 64, 0, stream>>>(h_cur, gstart, pooled);
  k_mlp<<<(GG+255)/256, 256, 0, stream>>>(pooled, W1, b1, W2, b2, out);
}

// Round 8
// 629.518 us; speedup vs baseline: 1.4300x; 1.1454x over previous
//
#include <hip/hip_runtime.h>

#define NN 150000
#define EE 600000
#define HH 4
#define CC 64
#define GG 4096
#define INF 9

typedef __attribute__((ext_vector_type(8))) short bf16x8;
typedef __attribute__((ext_vector_type(4))) float f32x4;

__device__ __forceinline__ float lrelu(float a){ return a > 0.f ? a : 0.2f*a; }
__device__ __forceinline__ float b2f(unsigned short u){ return __uint_as_float((unsigned)u << 16); }
__device__ __forceinline__ unsigned short f2b(float f){
  unsigned u = __float_as_uint(f);
  return (unsigned short)((u + 0x7fff + ((u >> 16) & 1)) >> 16);   // RNE
}

// ---------------- CSR build ----------------
__global__ __launch_bounds__(256) void k_count(const int* __restrict__ dst, int* __restrict__ deg){
  int e = blockIdx.x*256 + threadIdx.x;
  if (e < EE) atomicAdd(&deg[dst[e]], 1);
}

__global__ __launch_bounds__(256) void k_scan1(const int* __restrict__ deg, int* __restrict__ excl, int* __restrict__ bsum){
  __shared__ int s[256];
  int tid = threadIdx.x, gid = blockIdx.x*256 + tid;
  int v = (gid < NN) ? deg[gid] : 0;
  s[tid] = v; __syncthreads();
  for (int off = 1; off < 256; off <<= 1){
    int t = (tid >= off) ? s[tid-off] : 0; __syncthreads();
    s[tid] += t; __syncthreads();
  }
  if (gid < NN) excl[gid] = s[tid] - v;
  if (tid == 255) bsum[blockIdx.x] = s[255];
}

__global__ __launch_bounds__(1024) void k_scan2(int* __restrict__ bsum, int nb){
  __shared__ int s[1024];
  int tid = threadIdx.x;
  int v = (tid < nb) ? bsum[tid] : 0;
  s[tid] = v; __syncthreads();
  for (int off = 1; off < 1024; off <<= 1){
    int t = (tid >= off) ? s[tid-off] : 0; __syncthreads();
    s[tid] += t; __syncthreads();
  }
  if (tid < nb) bsum[tid] = s[tid] - v;
}

__global__ __launch_bounds__(256) void k_scan3(int* __restrict__ rp, const int* __restrict__ bsum){
  int gid = blockIdx.x*256 + threadIdx.x;
  if (gid < NN) rp[gid] += bsum[blockIdx.x];
  if (gid == 0) rp[NN] = EE;
}

__global__ __launch_bounds__(256) void k_fill(const int* __restrict__ src, const int* __restrict__ dst,
                                              const int* __restrict__ rp, int* __restrict__ fill,
                                              int* __restrict__ col){
  int e = blockIdx.x*256 + threadIdx.x;
  if (e < EE){
    int d = dst[e];
    int pos = rp[d] + atomicAdd(&fill[d], 1);
    col[pos] = src[e];
  }
}

__global__ __launch_bounds__(256) void k_gstart(const int* __restrict__ batch, int* __restrict__ gstart){
  int g = blockIdx.x*256 + threadIdx.x;
  if (g > GG) return;
  int lo = 0, hi = NN;
  while (lo < hi){ int mid = (lo+hi) >> 1; if (batch[mid] < g) lo = mid+1; else hi = mid; }
  gstart[g] = lo;
}

// ---------------- fold weights (logits folds + layer-0 stack) ----------------
__global__ __launch_bounds__(256) void k_fold(const float* __restrict__ g0W, const float* __restrict__ g0as,
    const float* __restrict__ g0ad, const float* __restrict__ gW, const float* __restrict__ gas,
    const float* __restrict__ gad, float* __restrict__ Wa0, float* __restrict__ Wa,
    float* __restrict__ Wstk0){
  const int OFF1 = 72, OFF2 = OFF1 + 1536, OFF3 = OFF2 + 2304;
  int t = blockIdx.x*256 + threadIdx.x;
  if (t < OFF1){
    int k = t >> 3, j = t & 7, h = j & 3;
    const float* a = (j < 4) ? g0as : g0ad;
    float s = 0.f;
    for (int c = 0; c < 64; c++) s += g0W[k*256 + h*64 + c] * a[h*64 + c];
    Wa0[t] = s;
  } else if (t < OFF2){
    int u = t - OFF1;
    int i = u / 512, r = u % 512, k = r >> 3, j = r & 7, h = j & 3;
    const float* a = ((j < 4) ? gas : gad) + (size_t)i*256;
    float s = 0.f;
    for (int c = 0; c < 64; c++) s += gW[(size_t)i*16384 + k*256 + h*64 + c] * a[h*64 + c];
    Wa[u] = s;
  } else if (t < OFF3){
    int u = t - OFF2;           // u = k*64 + j, k = h*9+c
    int k = u >> 6, j = u & 63;
    int h = k / 9, c = k - h*9;
    Wstk0[u] = 0.25f * g0W[c*256 + h*64 + j];
  }
}

// ---------------- fold W into MFMA fragment order, split bf16 hi/lo ----------------
// Wf[(i*16384) + ((c*8+s)*64 + l)*8 + b] = bf16 of 0.25*gW[i][ci][h*64+j],
//   k = s*32 + (l>>4)*8 + b (h = k>>6, ci = k&63), j = c*16 + (l&15)
__global__ __launch_bounds__(256) void k_foldB(const float* __restrict__ gW,
    unsigned short* __restrict__ Wfhi, unsigned short* __restrict__ Wflo){
  int t = blockIdx.x*256 + threadIdx.x;
  if (t >= 3*4*8*64) return;
  int l = t & 63, s = (t >> 6) & 7, c = (t >> 9) & 3, i = t >> 11;
  size_t base = (size_t)i*16384 + (size_t)(((c*8 + s)*64 + l))*8;
  #pragma unroll
  for (int b = 0; b < 8; b++){
    int k = s*32 + ((l >> 4) << 3) + b;
    int h = k >> 6, ci = k & 63;
    int j = (c << 4) + (l & 15);
    float v = 0.25f * gW[(size_t)i*16384 + ci*256 + h*64 + j];
    unsigned short hi = f2b(v);
    unsigned short lo = f2b(v - b2f(hi));
    Wfhi[base + b] = hi;
    Wflo[base + b] = lo;
  }
}

// ---------------- logits (layer 0 only) ----------------
__global__ __launch_bounds__(256) void k_logits9(const float* __restrict__ hin, const float* __restrict__ Wa,
                                                 float* __restrict__ lg){
  int idx = blockIdx.x*256 + threadIdx.x;
  int node = idx >> 3, j = idx & 7;
  if (node >= NN) return;
  const float* r = hin + (size_t)node*INF;
  float s = 0.f;
  #pragma unroll
  for (int k = 0; k < INF; k++) s += r[k] * Wa[k*8 + j];
  lg[(size_t)node*8 + j] = s;
}

// ---------------- layer-0 aggregation (f32 x, f32 agg32[N,36]), batch-4 pipelined ----------------
__global__ __launch_bounds__(256) void k_aggA9(const float* __restrict__ hin, const float* __restrict__ lg,
     const int* __restrict__ rp, const int* __restrict__ col, float* __restrict__ agg){
  int node = (blockIdx.x*256 + threadIdx.x) >> 6;
  int lane = threadIdx.x & 63;
  if (node >= NN) return;
  node = __builtin_amdgcn_readfirstlane(node);
  int rb = rp[node], re = rp[node+1];
  float4 esn = *(const float4*)(lg + (size_t)node*8);
  float4 edt = *(const float4*)(lg + (size_t)node*8 + 4);
  float edn[4] = {edt.x, edt.y, edt.z, edt.w};

  float den[4], acc[4];
  {
    float xv = (lane < INF) ? hin[(size_t)node*INF + lane] : 0.f;
    float a[4] = {esn.x, esn.y, esn.z, esn.w};
    #pragma unroll
    for (int h = 0; h < 4; h++){
      float ex = __expf(lrelu(a[h] + edn[h]));
      den[h] = ex; acc[h] = ex * xv;
    }
  }
  for (int e = rb; e < re; e += 4){
    int last = re - 1;
    int e1 = e+1 <= last ? e+1 : last;
    int e2 = e+2 <= last ? e+2 : last;
    int e3 = e+3 <= last ? e+3 : last;
    int s0 = col[e], s1 = col[e1], s2 = col[e2], s3 = col[e3];
    float4 t0 = *(const float4*)(lg + (size_t)s0*8);
    float4 t1 = *(const float4*)(lg + (size_t)s1*8);
    float4 t2 = *(const float4*)(lg + (size_t)s2*8);
    float4 t3 = *(const float4*)(lg + (size_t)s3*8);
    float x0 = (lane < INF) ? hin[(size_t)s0*INF + lane] : 0.f;
    float x1 = (lane < INF) ? hin[(size_t)s1*INF + lane] : 0.f;
    float x2 = (lane < INF) ? hin[(size_t)s2*INF + lane] : 0.f;
    float x3 = (lane < INF) ? hin[(size_t)s3*INF + lane] : 0.f;
    int n = re - e;
    { float a[4]={t0.x,t0.y,t0.z,t0.w};
      #pragma unroll
      for (int h=0;h<4;h++){ float ex=__expf(lrelu(a[h]+edn[h])); den[h]+=ex; acc[h]+=ex*x0; } }
    if (n > 1){ float a[4]={t1.x,t1.y,t1.z,t1.w};
      #pragma unroll
      for (int h=0;h<4;h++){ float ex=__expf(lrelu(a[h]+edn[h])); den[h]+=ex; acc[h]+=ex*x1; } }
    if (n > 2){ float a[4]={t2.x,t2.y,t2.z,t2.w};
      #pragma unroll
      for (int h=0;h<4;h++){ float ex=__expf(lrelu(a[h]+edn[h])); den[h]+=ex; acc[h]+=ex*x2; } }
    if (n > 3){ float a[4]={t3.x,t3.y,t3.z,t3.w};
      #pragma unroll
      for (int h=0;h<4;h++){ float ex=__expf(lrelu(a[h]+edn[h])); den[h]+=ex; acc[h]+=ex*x3; } }
  }
  if (lane < INF){
    float* ap = agg + (size_t)node*36 + lane;
    #pragma unroll
    for (int h = 0; h < 4; h++) ap[h*INF] = acc[h] / den[h];
  }
}

// ---------------- layers 1-3 aggregation (bf16 gather, bf16 agg[N,256]), batch-4 ----------------
__global__ __launch_bounds__(256) void k_aggAb(const unsigned short* __restrict__ hb, const float* __restrict__ lg,
     const int* __restrict__ rp, const int* __restrict__ col, unsigned short* __restrict__ aggb){
  int node = (blockIdx.x*256 + threadIdx.x) >> 6;
  int lane = threadIdx.x & 63;
  if (node >= NN) return;
  node = __builtin_amdgcn_readfirstlane(node);
  int rb = rp[node], re = rp[node+1];
  float4 esn = *(const float4*)(lg + (size_t)node*8);
  float4 edt = *(const float4*)(lg + (size_t)node*8 + 4);
  float edn[4] = {edt.x, edt.y, edt.z, edt.w};

  float den[4], acc[4];
  {
    float xv = b2f(hb[(size_t)node*64 + lane]);
    float a[4] = {esn.x, esn.y, esn.z, esn.w};
    #pragma unroll
    for (int h = 0; h < 4; h++){
      float ex = __expf(lrelu(a[h] + edn[h]));
      den[h] = ex; acc[h] = ex * xv;
    }
  }
  for (int e = rb; e < re; e += 4){
    int last = re - 1;
    int e1 = e+1 <= last ? e+1 : last;
    int e2 = e+2 <= last ? e+2 : last;
    int e3 = e+3 <= last ? e+3 : last;
    int s0 = col[e], s1 = col[e1], s2 = col[e2], s3 = col[e3];
    float4 t0 = *(const float4*)(lg + (size_t)s0*8);
    float4 t1 = *(const float4*)(lg + (size_t)s1*8);
    float4 t2 = *(const float4*)(lg + (size_t)s2*8);
    float4 t3 = *(const float4*)(lg + (size_t)s3*8);
    float x0 = b2f(hb[(size_t)s0*64 + lane]);
    float x1 = b2f(hb[(size_t)s1*64 + lane]);
    float x2 = b2f(hb[(size_t)s2*64 + lane]);
    float x3 = b2f(hb[(size_t)s3*64 + lane]);
    int n = re - e;
    { float a[4]={t0.x,t0.y,t0.z,t0.w};
      #pragma unroll
      for (int h=0;h<4;h++){ float ex=__expf(lrelu(a[h]+edn[h])); den[h]+=ex; acc[h]+=ex*x0; } }
    if (n > 1){ float a[4]={t1.x,t1.y,t1.z,t1.w};
      #pragma unroll
      for (int h=0;h<4;h++){ float ex=__expf(lrelu(a[h]+edn[h])); den[h]+=ex; acc[h]+=ex*x1; } }
    if (n > 2){ float a[4]={t2.x,t2.y,t2.z,t2.w};
      #pragma unroll
      for (int h=0;h<4;h++){ float ex=__expf(lrelu(a[h]+edn[h])); den[h]+=ex; acc[h]+=ex*x2; } }
    if (n > 3){ float a[4]={t3.x,t3.y,t3.z,t3.w};
      #pragma unroll
      for (int h=0;h<4;h++){ float ex=__expf(lrelu(a[h]+edn[h])); den[h]+=ex; acc[h]+=ex*x3; } }
  }
  #pragma unroll
  for (int h = 0; h < 4; h++)
    aggb[(size_t)node*256 + h*64 + lane] = f2b(acc[h] / den[h]);
}

// ---------------- layer-0 transform (f32, VALU) + epilogue + layer-1 logits ----------------
__global__ __launch_bounds__(256) void k_gemmB36(const float* __restrict__ agg, const float* __restrict__ Ws,
    const float* __restrict__ bias, const float* __restrict__ gma, const float* __restrict__ bta,
    const float* __restrict__ mea, const float* __restrict__ var,
    float* __restrict__ hout, unsigned short* __restrict__ hbf,
    const float* __restrict__ WaN, float* __restrict__ lg){
  __shared__ float xs[64*68];
  __shared__ float ws[64*68];
  __shared__ float wal[512];
  int t = threadIdx.x;
  int base = blockIdx.x * 64;
  int r = t >> 4, c2 = t & 15;
  for (int i = t; i < 512; i += 256) wal[i] = WaN[i];

  for (int i = t; i < 64*9; i += 256){
    int nd = i / 9, kk = i - nd*9;
    float4 v = {0.f,0.f,0.f,0.f};
    if (base + nd < NN) v = *(const float4*)(agg + (size_t)(base+nd)*36 + kk*4);
    *(float4*)(xs + nd*44 + kk*4) = v;
  }
  for (int i = t; i < 36*16; i += 256){
    int k = i >> 4, c4 = i & 15;
    *(float4*)(ws + k*68 + c4*4) = *(const float4*)(Ws + (size_t)k*64 + c4*4);
  }
  __syncthreads();

  float acc[4][4];
  #pragma unroll
  for (int i = 0; i < 4; i++)
    #pragma unroll
    for (int u = 0; u < 4; u++) acc[i][u] = 0.f;

  for (int k4 = 0; k4 < 36; k4 += 4){
    float4 xv[4], wv[4];
    #pragma unroll
    for (int i = 0; i < 4; i++) xv[i] = *(const float4*)(xs + (4*r+i)*44 + k4);
    #pragma unroll
    for (int u = 0; u < 4; u++) wv[u] = *(const float4*)(ws + (k4+u)*68 + 4*c2);
    #pragma unroll
    for (int i = 0; i < 4; i++){
      float xr[4] = {xv[i].x, xv[i].y, xv[i].z, xv[i].w};
      #pragma unroll
      for (int u = 0; u < 4; u++){
        acc[i][0] += xr[u]*wv[u].x; acc[i][1] += xr[u]*wv[u].y;
        acc[i][2] += xr[u]*wv[u].z; acc[i][3] += xr[u]*wv[u].w;
      }
    }
  }

  int cb = 4*c2;
  float4 bi = *(const float4*)(bias + cb);
  float4 gm = *(const float4*)(gma + cb);
  float4 bt = *(const float4*)(bta + cb);
  float4 me = *(const float4*)(mea + cb);
  float4 va = *(const float4*)(var + cb);
  float sc0 = rsqrtf(va.x + 1e-5f)*gm.x, sc1 = rsqrtf(va.y + 1e-5f)*gm.y;
  float sc2 = rsqrtf(va.z + 1e-5f)*gm.z, sc3 = rsqrtf(va.w + 1e-5f)*gm.w;
  __syncthreads();
  #pragma unroll
  for (int i = 0; i < 4; i++){
    int node = base + 4*r + i;
    if (node < NN){
      float o0 = (acc[i][0] + bi.x - me.x)*sc0 + bt.x;
      float o1 = (acc[i][1] + bi.y - me.y)*sc1 + bt.y;
      float o2 = (acc[i][2] + bi.z - me.z)*sc2 + bt.z;
      float o3 = (acc[i][3] + bi.w - me.w)*sc3 + bt.w;
      o0 = o0 > 0.f ? o0 : (__expf(o0) - 1.f);
      o1 = o1 > 0.f ? o1 : (__expf(o1) - 1.f);
      o2 = o2 > 0.f ? o2 : (__expf(o2) - 1.f);
      o3 = o3 > 0.f ? o3 : (__expf(o3) - 1.f);
      float4 st = {o0, o1, o2, o3};
      *(float4*)(hout + (size_t)node*64 + cb) = st;
      uint2 pb = { (unsigned)f2b(o0) | ((unsigned)f2b(o1) << 16),
                   (unsigned)f2b(o2) | ((unsigned)f2b(o3) << 16) };
      *(uint2*)(hbf + (size_t)node*64 + cb) = pb;
      *(float4*)(xs + (4*r+i)*68 + cb) = st;
    }
  }
  __syncthreads();
  int nd = t >> 2, jq = (t & 3) * 2;
  int node = base + nd;
  if (node < NN){
    float s0 = 0.f, s1 = 0.f;
    #pragma unroll 4
    for (int k = 0; k < 64; k += 4){
      float4 xv = *(const float4*)(xs + nd*68 + k);
      const float* w0 = wal + k*8 + jq;
      s0 += xv.x*w0[0] + xv.y*w0[8] + xv.z*w0[16] + xv.w*w0[24];
      s1 += xv.x*w0[1] + xv.y*w0[9] + xv.z*w0[17] + xv.w*w0[25];
    }
    float2 sv = {s0, s1};
    *(float2*)(lg + (size_t)node*8 + jq) = sv;
  }
}

// ---------------- layers 1-3 transform: MFMA, split-precision W ----------------
// Block: 64 nodes x 64 cols, 4 waves; wave w -> node-tile rows 16w..16w+15, all 64 cols.
// A (agg bf16) loaded global->fragments (no reuse -> no LDS). B = Wfhi/Wflo in fragment order.
// acc = A@Whi + A@Wlo in separate f32 accumulators (W quantization error ~2^-18).
// Epilogue via LDS: scatter D, coalesced BN/ELU/residual pass, then next-layer logits.
template<bool LOGITS>
__global__ __launch_bounds__(256) void k_gemmBM(const unsigned short* __restrict__ aggb,
    const unsigned short* __restrict__ Wfhi, const unsigned short* __restrict__ Wflo,
    const float* __restrict__ bias, const float* __restrict__ gma, const float* __restrict__ bta,
    const float* __restrict__ mea, const float* __restrict__ var,
    const float* __restrict__ hres, float* __restrict__ hout, unsigned short* __restrict__ hbf,
    const float* __restrict__ WaN, float* __restrict__ lg){
  __shared__ float xs[64*68];
  __shared__ float wal[512];
  int t = threadIdx.x, lane = t & 63, w = t >> 6;
  int base = blockIdx.x * 64;
  if (LOGITS){ for (int i = t; i < 512; i += 256) wal[i] = WaN[i]; }

  // A fragments: node = base+16w+(lane&15), k = s*32 + (lane>>4)*8 + 0..7
  int anode = base + (w << 4) + (lane & 15);
  if (anode >= NN) anode = NN - 1;
  const unsigned short* ap = aggb + (size_t)anode*256 + ((lane >> 4) << 3);
  bf16x8 af[8];
  #pragma unroll
  for (int s = 0; s < 8; s++) af[s] = *(const bf16x8*)(ap + s*32);

  f32x4 acch[4], accl[4];
  #pragma unroll
  for (int c = 0; c < 4; c++){ acch[c] = (f32x4)0.f; accl[c] = (f32x4)0.f; }

  #pragma unroll
  for (int s = 0; s < 8; s++){
    #pragma unroll
    for (int c = 0; c < 4; c++){
      int fidx = ((c*8 + s)*64 + lane)*8;
      bf16x8 bh = *(const bf16x8*)(Wfhi + fidx);
      bf16x8 bl = *(const bf16x8*)(Wflo + fidx);
      acch[c] = __builtin_amdgcn_mfma_f32_16x16x32_bf16(af[s], bh, acch[c], 0, 0, 0);
      accl[c] = __builtin_amdgcn_mfma_f32_16x16x32_bf16(af[s], bl, accl[c], 0, 0, 0);
    }
  }

  // scatter D into xs: row = 16w + 4*(lane>>4)+r, col = c*16 + (lane&15)
  int rr = (w << 4) + ((lane >> 4) << 2);
  int cc = lane & 15;
  #pragma unroll
  for (int c = 0; c < 4; c++){
    #pragma unroll
    for (int r = 0; r < 4; r++)
      xs[(rr + r)*68 + (c << 4) + cc] = acch[c][r] + accl[c][r];
  }
  __syncthreads();

  // coalesced epilogue: bias + BN + ELU + residual; stores + write-back for logits
  for (int i = t; i < 64*64; i += 256){
    int nd = i >> 6, j = i & 63;
    int node = base + nd;
    if (node < NN){
      float o = xs[nd*68 + j] + bias[j];
      o = (o - mea[j]) * rsqrtf(var[j] + 1e-5f) * gma[j] + bta[j];
      o = o > 0.f ? o : (__expf(o) - 1.f);
      o += hres[(size_t)node*64 + j];
      hout[(size_t)node*64 + j] = o;
      if (LOGITS){
        hbf[(size_t)node*64 + j] = f2b(o);
        xs[nd*68 + j] = o;
      }
    }
  }
  if (LOGITS){
    __syncthreads();
    int nd = t >> 2, jq = (t & 3) * 2;
    int node = base + nd;
    if (node < NN){
      float s0 = 0.f, s1 = 0.f;
      #pragma unroll 4
      for (int k = 0; k < 64; k += 4){
        float4 xv = *(const float4*)(xs + nd*68 + k);
        const float* w0 = wal + k*8 + jq;
        s0 += xv.x*w0[0] + xv.y*w0[8] + xv.z*w0[16] + xv.w*w0[24];
        s1 += xv.x*w0[1] + xv.y*w0[9] + xv.z*w0[17] + xv.w*w0[25];
      }
      float2 sv = {s0, s1};
      *(float2*)(lg + (size_t)node*8 + jq) = sv;
    }
  }
}

// ---------------- pooling ----------------
__global__ __launch_bounds__(64) void k_pool(const float* __restrict__ h, const int* __restrict__ gstart,
                                             float* __restrict__ pooled){
  int g = blockIdx.x; int lane = threadIdx.x;
  int beg = gstart[g], end = gstart[g+1];
  float acc = 0.f;
  for (int n = beg; n < end; n++) acc += h[(size_t)n*64 + lane];
  float cnt = (float)(end - beg);
  pooled[(size_t)g*64 + lane] = acc / fmaxf(cnt, 1.f);
}

// ---------------- output MLP ----------------
__global__ __launch_bounds__(256) void k_mlp(const float* __restrict__ pooled, const float* __restrict__ W1,
                                             const float* __restrict__ b1, const float* __restrict__ W2,
                                             const float* __restrict__ b2, float* __restrict__ out){
  int g = blockIdx.x*256 + threadIdx.x;
  if (g >= GG) return;
  const float* p = pooled + (size_t)g*64;
  float o = 0.f;
  for (int j = 0; j < 32; j++){
    float z = b1[j];
    for (int c = 0; c < 64; c++) z += p[c] * W1[c*32 + j];
    z = z > 0.f ? z : (__expf(z) - 1.f);
    o += z * W2[j];
  }
  out[g] = o + b2[0];
}

extern "C" void kernel_launch(void* const* d_in, const int* in_sizes, int n_in,
                              void* d_out, int out_size, void* d_ws, size_t ws_size,
                              hipStream_t stream) {
  const float* x    = (const float*)d_in[0];
  const int*   ei   = (const int*)d_in[1];
  const int*   batch= (const int*)d_in[2];
  const float* g0W  = (const float*)d_in[3];
  const float* g0as = (const float*)d_in[4];
  const float* g0ad = (const float*)d_in[5];
  const float* g0b  = (const float*)d_in[6];
  const float* bn0g = (const float*)d_in[7];
  const float* bn0b = (const float*)d_in[8];
  const float* bn0m = (const float*)d_in[9];
  const float* bn0v = (const float*)d_in[10];
  const float* gW   = (const float*)d_in[11];
  const float* gas  = (const float*)d_in[12];
  const float* gad  = (const float*)d_in[13];
  const float* gb   = (const float*)d_in[14];
  const float* bng  = (const float*)d_in[15];
  const float* bnb  = (const float*)d_in[16];
  const float* bnm  = (const float*)d_in[17];
  const float* bnv  = (const float*)d_in[18];
  const float* W1   = (const float*)d_in[19];
  const float* b1   = (const float*)d_in[20];
  const float* W2   = (const float*)d_in[21];
  const float* b2   = (const float*)d_in[22];
  float* out = (float*)d_out;
  (void)in_sizes; (void)n_in; (void)out_size; (void)ws_size;

  char* base = (char*)d_ws; size_t off = 0;
  auto alloc = [&](size_t b)->void*{ void* p = base + off; off = (off + b + 255) & ~(size_t)255; return p; };
  unsigned short* aggb = (unsigned short*)alloc((size_t)NN*256*2);  // 76.8 MB
  float* agg32  = (float*)alloc((size_t)NN*36*4);                   // 21.6 MB
  float* h_cur  = (float*)alloc((size_t)NN*64*4);                   // 38.4 MB
  unsigned short* hbf = (unsigned short*)alloc((size_t)NN*64*2);    // 19.2 MB
  float* lg     = (float*)alloc((size_t)NN*8*4);                    // 4.8 MB
  int*   deg    = (int*)alloc((size_t)NN*4);
  int*   fill   = (int*)alloc((size_t)NN*4);
  int*   rp     = (int*)alloc((size_t)(NN+1)*4);
  int*   col    = (int*)alloc((size_t)EE*4);
  int*   bsum   = (int*)alloc(1024*4);
  int*   gstart = (int*)alloc((size_t)(GG+1)*4);
  float* pooled = (float*)alloc((size_t)GG*64*4);
  float* Wa0    = (float*)alloc((size_t)72*4);
  float* Wa     = (float*)alloc((size_t)1536*4);
  float* Wstk0  = (float*)alloc((size_t)2304*4);
  unsigned short* Wfhi = (unsigned short*)alloc((size_t)3*16384*2);
  unsigned short* Wflo = (unsigned short*)alloc((size_t)3*16384*2);

  const int* esrc = ei;
  const int* edst = ei + EE;

  hipMemsetAsync(deg, 0, (size_t)NN*4, stream);
  hipMemsetAsync(fill, 0, (size_t)NN*4, stream);

  int nb1 = (NN + 255)/256;
  k_count<<<(EE+255)/256, 256, 0, stream>>>(edst, deg);
  k_scan1<<<nb1, 256, 0, stream>>>(deg, rp, bsum);
  k_scan2<<<1, 1024, 0, stream>>>(bsum, nb1);
  k_scan3<<<nb1, 256, 0, stream>>>(rp, bsum);
  k_fill<<<(EE+255)/256, 256, 0, stream>>>(esrc, edst, rp, fill, col);
  k_gstart<<<(GG+256)/256, 256, 0, stream>>>(batch, gstart);
  k_fold<<<16, 256, 0, stream>>>(g0W, g0as, g0ad, gW, gas, gad, Wa0, Wa, Wstk0);
  k_foldB<<<24, 256, 0, stream>>>(gW, Wfhi, Wflo);

  int nlog  = (NN*8 + 255)/256;   // 4688
  int nwave = NN/4;               // 37500
  int ngB   = (NN + 63)/64;       // 2344

  // layer 0 (layer-1 logits fused into gemmB36 via WaN = Wa[0])
  k_logits9<<<nlog, 256, 0, stream>>>(x, Wa0, lg);
  k_aggA9<<<nwave, 256, 0, stream>>>(x, lg, rp, col, agg32);
  k_gemmB36<<<ngB, 256, 0, stream>>>(agg32, Wstk0, g0b, bn0g, bn0b, bn0m, bn0v,
                                     h_cur, hbf, Wa, lg);
  // layers 1..3 (MFMA transform)
  for (int i = 0; i < 3; i++){
    k_aggAb<<<nwave, 256, 0, stream>>>(hbf, lg, rp, col, aggb);
    if (i < 2)
      k_gemmBM<true><<<ngB, 256, 0, stream>>>(aggb, Wfhi + (size_t)i*16384, Wflo + (size_t)i*16384,
                                              gb + (size_t)i*64,
                                              bng + (size_t)i*64, bnb + (size_t)i*64,
                                              bnm + (size_t)i*64, bnv + (size_t)i*64,
                                              h_cur, h_cur, hbf, Wa + (size_t)(i+1)*512, lg);
    else
      k_gemmBM<false><<<ngB, 256, 0, stream>>>(aggb, Wfhi + (size_t)i*16384, Wflo + (size_t)i*16384,
                                               gb + (size_t)i*64,
                                               bng + (size_t)i*64, bnb + (size_t)i*64,
                                               bnm + (size_t)i*64, bnv + (size_t)i*64,
                                               h_cur, h_cur, hbf, nullptr, nullptr);
  }

  k_pool<<<GG, 64, 0, stream>>>(h_cur, gstart, pooled);
  k_mlp<<<(GG+255)/256, 256, 0, stream>>>(pooled, W1, b1, W2, b2, out);
}